// Round 1
// baseline (1795.764 us; speedup 1.0000x reference)
//
#include <hip/hip_runtime.h>

#define NN 40000
#define EE 400000

typedef short short8 __attribute__((ext_vector_type(8)));
typedef float f32x4 __attribute__((ext_vector_type(4)));
typedef unsigned short ushort4_ __attribute__((ext_vector_type(4)));

__device__ __forceinline__ unsigned short f2bf(float f) {
  unsigned int u = __float_as_uint(f);
  u = (u + 0x7FFFu + ((u >> 16) & 1u)) >> 16;
  return (unsigned short)u;
}

// ---- f32 -> bf16 for the 6 node-feature matrices --------------------------
__global__ __launch_bounds__(256) void k_convx(
    const float* __restrict__ x0, const float* __restrict__ x1, const float* __restrict__ x2,
    const float* __restrict__ x3, const float* __restrict__ x4, const float* __restrict__ x5,
    unsigned short* __restrict__ xb) {
  int z = blockIdx.y;
  const float* x;
  switch (z) { case 0: x = x0; break; case 1: x = x1; break; case 2: x = x2; break;
               case 3: x = x3; break; case 4: x = x4; break; default: x = x5; break; }
  size_t i = ((size_t)blockIdx.x * 256 + threadIdx.x) * 4;
  f32x4 v = *(const f32x4*)(x + i);
  ushort4_ o;
  o[0] = f2bf(v[0]); o[1] = f2bf(v[1]); o[2] = f2bf(v[2]); o[3] = f2bf(v[3]);
  *(ushort4_*)(xb + (size_t)z * (NN * 256) + i) = o;
}

// ---- W -> bf16, k-tiled transposed: wt2[r][kt][n][k0] = W[r][kt*32+k0][n] --
__global__ __launch_bounds__(256) void k_wt2(const float* __restrict__ W,
                                             unsigned short* __restrict__ wt2) {
  int idx = blockIdx.x * 256 + threadIdx.x;  // < 262144
  int k0 = idx & 31, n = (idx >> 5) & 255, kt = (idx >> 13) & 7, r = idx >> 16;
  float v = W[((size_t)(r * 256) + (kt * 32 + k0)) * 256 + n];
  wt2[idx] = f2bf(v);
}

// ---- weff[q][f][j] = sum_c W[r][f][j*32+c] * att[r][j][c], q = r*2+side ----
__global__ __launch_bounds__(256) void k_weff(const float* __restrict__ W,
                                              const float* __restrict__ asrc,
                                              const float* __restrict__ adst,
                                              float* __restrict__ weff) {
  int idx = blockIdx.x * 256 + threadIdx.x;  // < 16384
  int j = idx & 7, f = (idx >> 3) & 255, q = idx >> 11;
  int r = q >> 1, side = q & 1;
  const float* att = side ? adst : asrc;
  const float* wrow = W + ((size_t)(r * 256) + f) * 256 + j * 32;
  const float* arow = att + (r * 8 + j) * 32;
  float s = 0.f;
#pragma unroll
  for (int c = 0; c < 32; ++c) s += wrow[c] * arow[c];
  weff[idx] = s;
}

// ---- CSR build ------------------------------------------------------------
__global__ __launch_bounds__(256) void k_zero(int* __restrict__ p, int n) {
  int i = blockIdx.x * 256 + threadIdx.x;
  if (i < n) p[i] = 0;
}

__global__ __launch_bounds__(256) void k_hist(
    const int* __restrict__ e0, const int* __restrict__ e1,
    const int* __restrict__ e2, const int* __restrict__ e3, int* __restrict__ cnt) {
  int r = blockIdx.y;
  const int* ei = (r == 0) ? e0 : (r == 1) ? e1 : (r == 2) ? e2 : e3;
  int e = blockIdx.x * 256 + threadIdx.x;
  if (e < EE) atomicAdd(&cnt[r * NN + ei[EE + e]], 1);
}

__global__ __launch_bounds__(1024) void k_scan(const int* __restrict__ cnt,
                                               int* __restrict__ rowptr,
                                               int* __restrict__ cursor) {
  int r = blockIdx.x;
  const int* c = cnt + r * NN;
  int* rp = rowptr + r * (NN + 1);
  int* cur = cursor + r * NN;
  __shared__ int part[1024];
  int t = threadIdx.x;
  const int per = 40;  // 1024*40 >= 40000
  int base = t * per;
  int sum = 0;
  for (int i = 0; i < per; ++i) { int idx = base + i; if (idx < NN) sum += c[idx]; }
  part[t] = sum;
  __syncthreads();
  for (int o = 1; o < 1024; o <<= 1) {
    int v = (t >= o) ? part[t - o] : 0;
    __syncthreads();
    part[t] += v;
    __syncthreads();
  }
  int run = part[t] - sum;  // exclusive prefix
  for (int i = 0; i < per; ++i) {
    int idx = base + i;
    if (idx < NN) { rp[idx] = run; cur[idx] = run; run += c[idx]; }
  }
  if (t == 1023) rp[NN] = part[1023];
}

__global__ __launch_bounds__(256) void k_scatter(
    const int* __restrict__ e0, const int* __restrict__ e1,
    const int* __restrict__ e2, const int* __restrict__ e3,
    int* __restrict__ cursor, int* __restrict__ adj) {
  int r = blockIdx.y;
  const int* ei = (r == 0) ? e0 : (r == 1) ? e1 : (r == 2) ? e2 : e3;
  int e = blockIdx.x * 256 + threadIdx.x;
  if (e < EE) {
    int s = ei[e], d = ei[EE + e];
    int pos = atomicAdd(&cursor[r * NN + d], 1);
    adj[(size_t)r * EE + pos] = s;
  }
}

// ---- attention logits: al[z][n][8] = x @ weff[q], z = g*8 + r*2 + side ----
__global__ __launch_bounds__(256) void k_al(
    const float* __restrict__ x0, const float* __restrict__ x1, const float* __restrict__ x2,
    const float* __restrict__ x3, const float* __restrict__ x4, const float* __restrict__ x5,
    const float* __restrict__ weff, float* __restrict__ al) {
  int z = blockIdx.y;
  int g = z >> 3, q = z & 7, r = q >> 1, side = q & 1;
  int type = side ? ((r == 0) ? 1 : (r == 2) ? 2 : 0)
                  : ((r == 1) ? 1 : (r == 3) ? 2 : 0);
  int t = g * 3 + type;
  const float* x;
  switch (t) { case 0: x = x0; break; case 1: x = x1; break; case 2: x = x2; break;
               case 3: x = x3; break; case 4: x = x4; break; default: x = x5; break; }
  int wave = threadIdx.x >> 6, lane = threadIdx.x & 63;
  int n = blockIdx.x * 4 + wave;
  f32x4 xv = *(const f32x4*)(x + (size_t)n * 256 + lane * 4);
  const float* we = weff + q * 2048 + lane * 32;
  float p[8];
#pragma unroll
  for (int j = 0; j < 8; ++j)
    p[j] = xv[0] * we[j] + xv[1] * we[8 + j] + xv[2] * we[16 + j] + xv[3] * we[24 + j];
#pragma unroll
  for (int m = 1; m < 64; m <<= 1) {
#pragma unroll
    for (int j = 0; j < 8; ++j) p[j] += __shfl_xor(p[j], m, 64);
  }
  if (lane == 0) {
    float* o = al + ((size_t)z * NN + n) * 8;
#pragma unroll
    for (int j = 0; j < 8; ++j) o[j] = p[j];
  }
}

// ---- bf16 MFMA GEMM: h[40000][256] = xb @ W  (BM=64, BN=256, BK=32) -------
__global__ __launch_bounds__(256) void k_gemm(const unsigned short* __restrict__ xb,
                                              const unsigned short* __restrict__ wt2,
                                              float* __restrict__ h) {
  __shared__ __attribute__((aligned(16))) unsigned short Alds[64][40];   // pad 32->40
  __shared__ __attribute__((aligned(16))) unsigned short Blds[256][40];
  int tid = threadIdx.x;
  int wave = tid >> 6, lane = tid & 63;
  int l15 = lane & 15, l16 = lane >> 4;
  int row0 = blockIdx.x * 64;
  f32x4 acc[4][4] = {};
  int ar = tid >> 2, ac = (tid & 3) * 8;
  const unsigned short* aglob = xb + (size_t)(row0 + ar) * 256 + ac;
  for (int kt = 0; kt < 8; ++kt) {
    short8 av = *(const short8*)(aglob + kt * 32);
    *(short8*)(&Alds[ar][ac]) = av;
    const unsigned short* bsrc = wt2 + kt * (256 * 32);
#pragma unroll
    for (int i = 0; i < 4; ++i) {
      int cidx = tid + 256 * i;
      short8 bv = *(const short8*)(bsrc + cidx * 8);
      *(short8*)(&Blds[cidx >> 2][(cidx & 3) * 8]) = bv;
    }
    __syncthreads();
    short8 af[4], bf[4];
#pragma unroll
    for (int mt = 0; mt < 4; ++mt) af[mt] = *(const short8*)(&Alds[mt * 16 + l15][l16 * 8]);
#pragma unroll
    for (int nt = 0; nt < 4; ++nt) bf[nt] = *(const short8*)(&Blds[wave * 64 + nt * 16 + l15][l16 * 8]);
#pragma unroll
    for (int mt = 0; mt < 4; ++mt)
#pragma unroll
      for (int nt = 0; nt < 4; ++nt)
        acc[mt][nt] = __builtin_amdgcn_mfma_f32_16x16x32_bf16(af[mt], bf[nt], acc[mt][nt], 0, 0, 0);
    __syncthreads();
  }
#pragma unroll
  for (int mt = 0; mt < 4; ++mt)
#pragma unroll
    for (int nt = 0; nt < 4; ++nt)
#pragma unroll
      for (int rr = 0; rr < 4; ++rr)
        h[(size_t)(row0 + mt * 16 + l16 * 4 + rr) * 256 + wave * 64 + nt * 16 + l15] = acc[mt][nt][rr];
}

// ---- per-dst-node softmax + aggregation (one wave per node) ---------------
__global__ __launch_bounds__(256) void k_agg(
    const int* __restrict__ rowptr, const int* __restrict__ adj,
    const float* __restrict__ alsrc, const float* __restrict__ aldst,
    const float* __restrict__ h, const float* __restrict__ bias,
    float* __restrict__ out, int mode) {
  int wave = threadIdx.x >> 6, lane = threadIdx.x & 63;
  int d = blockIdx.x * 4 + wave;
  int hl = lane >> 3;
  int beg = rowptr[d], end = rowptr[d + 1];
  float adst = aldst[(size_t)d * 8 + hl];
  float eself = alsrc[(size_t)d * 8 + hl] + adst;
  eself = eself >= 0.f ? eself : 0.2f * eself;
  float m = eself;
  for (int j = beg; j < end; ++j) {
    int s = adj[j];
    float e = alsrc[(size_t)s * 8 + hl] + adst;
    e = e >= 0.f ? e : 0.2f * e;
    m = fmaxf(m, e);
  }
  float ssum = 0.f;
  f32x4 acc = {0.f, 0.f, 0.f, 0.f};
  {
    float w = __expf(eself - m);
    ssum += w;
    f32x4 hv = *(const f32x4*)(h + (size_t)d * 256 + lane * 4);
#pragma unroll
    for (int i = 0; i < 4; ++i) acc[i] += w * hv[i];
  }
  for (int j = beg; j < end; ++j) {
    int s = adj[j];
    float e = alsrc[(size_t)s * 8 + hl] + adst;
    e = e >= 0.f ? e : 0.2f * e;
    float w = __expf(e - m);
    ssum += w;
    f32x4 hv = *(const f32x4*)(h + (size_t)s * 256 + lane * 4);
#pragma unroll
    for (int i = 0; i < 4; ++i) acc[i] += w * hv[i];
  }
  float inv = 1.f / ssum;
  f32x4 bv = *(const f32x4*)(bias + lane * 4);
  f32x4 res;
#pragma unroll
  for (int i = 0; i < 4; ++i) res[i] = acc[i] * inv + bv[i];
  float* op = out + (size_t)d * 256 + lane * 4;
  if (mode == 1) {
    f32x4 prev = *(const f32x4*)op;
#pragma unroll
    for (int i = 0; i < 4; ++i) res[i] = 0.5f * (prev[i] + res[i]);
  }
  *(f32x4*)op = res;
}

extern "C" void kernel_launch(void* const* d_in, const int* in_sizes, int n_in,
                              void* d_out, int out_size, void* d_ws, size_t ws_size,
                              hipStream_t stream) {
  (void)in_sizes; (void)n_in; (void)out_size; (void)ws_size;
  const float* x[6];
  for (int i = 0; i < 6; ++i) x[i] = (const float*)d_in[i];
  const float* W = (const float*)d_in[6];
  const float* att_src = (const float*)d_in[7];
  const float* att_dst = (const float*)d_in[8];
  const float* bias = (const float*)d_in[9];
  const int* ei[4] = {(const int*)d_in[10], (const int*)d_in[11],
                      (const int*)d_in[12], (const int*)d_in[13]};
  float* out = (float*)d_out;

  char* ws = (char*)d_ws;
  size_t off = 0;
  auto take = [&](size_t bytes) -> char* {
    char* p = ws + off;
    off += (bytes + 255) & ~(size_t)255;
    return p;
  };
  unsigned short* xb = (unsigned short*)take(6ull * NN * 256 * 2);   // 122.9 MB
  float* h = (float*)take((size_t)NN * 256 * 4);                     // 41 MB
  float* al = (float*)take(16ull * NN * 8 * 4);                      // 20.5 MB
  unsigned short* wt2 = (unsigned short*)take(4ull * 8 * 256 * 32 * 2);
  float* weff = (float*)take(8ull * 256 * 8 * 4);
  int* cnt = (int*)take(4ull * NN * 4);
  int* rowptr = (int*)take(4ull * (NN + 1) * 4);
  int* cursor = (int*)take(4ull * NN * 4);
  int* adj = (int*)take(4ull * EE * 4);

  k_convx<<<dim3(10000, 6), 256, 0, stream>>>(x[0], x[1], x[2], x[3], x[4], x[5], xb);
  k_wt2<<<dim3(1024), 256, 0, stream>>>(W, wt2);
  k_weff<<<dim3(64), 256, 0, stream>>>(W, att_src, att_dst, weff);
  k_zero<<<dim3(625), 256, 0, stream>>>(cnt, 4 * NN);
  k_hist<<<dim3((EE + 255) / 256, 4), 256, 0, stream>>>(ei[0], ei[1], ei[2], ei[3], cnt);
  k_scan<<<dim3(4), 1024, 0, stream>>>(cnt, rowptr, cursor);
  k_scatter<<<dim3((EE + 255) / 256, 4), 256, 0, stream>>>(ei[0], ei[1], ei[2], ei[3], cursor, adj);
  k_al<<<dim3(10000, 16), 256, 0, stream>>>(x[0], x[1], x[2], x[3], x[4], x[5], weff, al);

  // relation -> src node type (0=paper,1=author,2=subject)
  const int srct[4] = {0, 1, 0, 2};
  // processing order per graph: rel0->author, rel1->paper(write), rel3->paper(combine), rel2->subject
  const int opr[4] = {0, 1, 3, 2};
  const int opsec[4] = {1, 0, 0, 2};
  const int opmode[4] = {0, 0, 1, 0};
  for (int g = 0; g < 2; ++g) {
    for (int k = 0; k < 4; ++k) {
      int r = opr[k];
      const unsigned short* xbp = xb + (size_t)(g * 3 + srct[r]) * (NN * 256);
      const unsigned short* wtp = wt2 + (size_t)r * (8 * 256 * 32);
      k_gemm<<<dim3(625), 256, 0, stream>>>(xbp, wtp, h);
      const float* alsrc = al + (size_t)(g * 8 + r * 2) * NN * 8;
      const float* aldst = al + (size_t)(g * 8 + r * 2 + 1) * NN * 8;
      float* outp = out + ((size_t)g * 3 * NN + (size_t)opsec[k] * NN) * 256;
      k_agg<<<dim3(10000), 256, 0, stream>>>(rowptr + r * (NN + 1), adj + (size_t)r * EE,
                                             alsrc, aldst, h, bias + r * 256, outp, opmode[k]);
    }
  }
}

// Round 2
// 1215.446 us; speedup vs baseline: 1.4775x; 1.4775x over previous
//
#include <hip/hip_runtime.h>

#define NN 40000
#define EE 400000

typedef short short8 __attribute__((ext_vector_type(8)));
typedef float f32x4 __attribute__((ext_vector_type(4)));
typedef unsigned short ushort4_ __attribute__((ext_vector_type(4)));

__device__ __forceinline__ unsigned short f2bf(float f) {
  unsigned int u = __float_as_uint(f);
  u = (u + 0x7FFFu + ((u >> 16) & 1u)) >> 16;
  return (unsigned short)u;
}

__device__ __forceinline__ f32x4 ld_bf4(const unsigned short* p) {
  ushort4_ u = *(const ushort4_*)p;
  f32x4 r;
  r[0] = __uint_as_float((unsigned int)u[0] << 16);
  r[1] = __uint_as_float((unsigned int)u[1] << 16);
  r[2] = __uint_as_float((unsigned int)u[2] << 16);
  r[3] = __uint_as_float((unsigned int)u[3] << 16);
  return r;
}

// ---- f32 -> bf16 for the 6 node-feature matrices --------------------------
__global__ __launch_bounds__(256) void k_convx(
    const float* __restrict__ x0, const float* __restrict__ x1, const float* __restrict__ x2,
    const float* __restrict__ x3, const float* __restrict__ x4, const float* __restrict__ x5,
    unsigned short* __restrict__ xb) {
  int z = blockIdx.y;
  const float* x;
  switch (z) { case 0: x = x0; break; case 1: x = x1; break; case 2: x = x2; break;
               case 3: x = x3; break; case 4: x = x4; break; default: x = x5; break; }
  size_t i = ((size_t)blockIdx.x * 256 + threadIdx.x) * 4;
  f32x4 v = *(const f32x4*)(x + i);
  ushort4_ o;
  o[0] = f2bf(v[0]); o[1] = f2bf(v[1]); o[2] = f2bf(v[2]); o[3] = f2bf(v[3]);
  *(ushort4_*)(xb + (size_t)z * (NN * 256) + i) = o;
}

// ---- W -> bf16, k-tiled transposed: wt2[r][kt][n][k0] = W[r][kt*32+k0][n] --
__global__ __launch_bounds__(256) void k_wt2(const float* __restrict__ W,
                                             unsigned short* __restrict__ wt2) {
  int idx = blockIdx.x * 256 + threadIdx.x;  // < 262144
  int k0 = idx & 31, n = (idx >> 5) & 255, kt = (idx >> 13) & 7, r = idx >> 16;
  float v = W[((size_t)(r * 256) + (kt * 32 + k0)) * 256 + n];
  wt2[idx] = f2bf(v);
}

// ---- weff[q][f][j] = sum_c W[r][f][j*32+c] * att[r][j][c], q = r*2+side ----
__global__ __launch_bounds__(256) void k_weff(const float* __restrict__ W,
                                              const float* __restrict__ asrc,
                                              const float* __restrict__ adst,
                                              float* __restrict__ weff) {
  int idx = blockIdx.x * 256 + threadIdx.x;  // < 16384
  int j = idx & 7, f = (idx >> 3) & 255, q = idx >> 11;
  int r = q >> 1, side = q & 1;
  const float* att = side ? adst : asrc;
  const float* wrow = W + ((size_t)(r * 256) + f) * 256 + j * 32;
  const float* arow = att + (r * 8 + j) * 32;
  float s = 0.f;
#pragma unroll
  for (int c = 0; c < 32; ++c) s += wrow[c] * arow[c];
  weff[idx] = s;
}

// ---- weff -> bf16 k-tiled B layout: weffb[kt][col][k0], col = q*8 + j ------
__global__ __launch_bounds__(256) void k_weffb(const float* __restrict__ weff,
                                               unsigned short* __restrict__ weffb) {
  int idx = blockIdx.x * 256 + threadIdx.x;  // < 16384
  int k0 = idx & 31, col = (idx >> 5) & 63, kt = idx >> 11;
  int q = col >> 3, j = col & 7;
  int f = kt * 32 + k0;
  weffb[idx] = f2bf(weff[(q * 256 + f) * 8 + j]);
}

// ---- CSR build ------------------------------------------------------------
__global__ __launch_bounds__(256) void k_zero(int* __restrict__ p, int n) {
  int i = blockIdx.x * 256 + threadIdx.x;
  if (i < n) p[i] = 0;
}

__global__ __launch_bounds__(256) void k_hist(
    const int* __restrict__ e0, const int* __restrict__ e1,
    const int* __restrict__ e2, const int* __restrict__ e3, int* __restrict__ cnt) {
  int r = blockIdx.y;
  const int* ei = (r == 0) ? e0 : (r == 1) ? e1 : (r == 2) ? e2 : e3;
  int e = blockIdx.x * 256 + threadIdx.x;
  if (e < EE) atomicAdd(&cnt[r * NN + ei[EE + e]], 1);
}

__global__ __launch_bounds__(1024) void k_scan(const int* __restrict__ cnt,
                                               int* __restrict__ rowptr,
                                               int* __restrict__ cursor) {
  int r = blockIdx.x;
  const int* c = cnt + r * NN;
  int* rp = rowptr + r * (NN + 1);
  int* cur = cursor + r * NN;
  __shared__ int part[1024];
  int t = threadIdx.x;
  const int per = 40;  // 1024*40 >= 40000
  int base = t * per;
  int sum = 0;
  for (int i = 0; i < per; ++i) { int idx = base + i; if (idx < NN) sum += c[idx]; }
  part[t] = sum;
  __syncthreads();
  for (int o = 1; o < 1024; o <<= 1) {
    int v = (t >= o) ? part[t - o] : 0;
    __syncthreads();
    part[t] += v;
    __syncthreads();
  }
  int run = part[t] - sum;  // exclusive prefix
  for (int i = 0; i < per; ++i) {
    int idx = base + i;
    if (idx < NN) { rp[idx] = run; cur[idx] = run; run += c[idx]; }
  }
  if (t == 1023) rp[NN] = part[1023];
}

__global__ __launch_bounds__(256) void k_scatter(
    const int* __restrict__ e0, const int* __restrict__ e1,
    const int* __restrict__ e2, const int* __restrict__ e3,
    int* __restrict__ cursor, int* __restrict__ adj) {
  int r = blockIdx.y;
  const int* ei = (r == 0) ? e0 : (r == 1) ? e1 : (r == 2) ? e2 : e3;
  int e = blockIdx.x * 256 + threadIdx.x;
  if (e < EE) {
    int s = ei[e], d = ei[EE + e];
    int pos = atomicAdd(&cursor[r * NN + d], 1);
    adj[(size_t)r * EE + pos] = s;
  }
}

// ---- attention logits via MFMA: alx[z][n][64] = xb[z] @ weffb --------------
// z = g*3 + type; col = q*8 + head, q = r*2 + side
__global__ __launch_bounds__(256) void k_algemm(const unsigned short* __restrict__ xb,
                                                const unsigned short* __restrict__ weffb,
                                                float* __restrict__ alx) {
  __shared__ __attribute__((aligned(16))) unsigned short Alds[64][40];
  __shared__ __attribute__((aligned(16))) unsigned short Blds[64][40];
  int z = blockIdx.y;
  const unsigned short* xbp = xb + (size_t)z * (NN * 256);
  float* outp = alx + (size_t)z * (NN * 64);
  int tid = threadIdx.x;
  int wave = tid >> 6, lane = tid & 63;
  int l15 = lane & 15, l16 = lane >> 4;
  int row0 = blockIdx.x * 64;
  f32x4 acc[4] = {};
  int ar = tid >> 2, ac = (tid & 3) * 8;
  const unsigned short* aglob = xbp + (size_t)(row0 + ar) * 256 + ac;
  for (int kt = 0; kt < 8; ++kt) {
    short8 av = *(const short8*)(aglob + kt * 32);
    *(short8*)(&Alds[ar][ac]) = av;
    short8 bv = *(const short8*)(weffb + kt * 2048 + tid * 8);
    *(short8*)(&Blds[tid >> 2][(tid & 3) * 8]) = bv;
    __syncthreads();
    short8 bf = *(const short8*)(&Blds[wave * 16 + l15][l16 * 8]);
#pragma unroll
    for (int mt = 0; mt < 4; ++mt) {
      short8 af = *(const short8*)(&Alds[mt * 16 + l15][l16 * 8]);
      acc[mt] = __builtin_amdgcn_mfma_f32_16x16x32_bf16(af, bf, acc[mt], 0, 0, 0);
    }
    __syncthreads();
  }
#pragma unroll
  for (int mt = 0; mt < 4; ++mt)
#pragma unroll
    for (int rr = 0; rr < 4; ++rr)
      outp[(size_t)(row0 + mt * 16 + l16 * 4 + rr) * 64 + wave * 16 + l15] = acc[mt][rr];
}

// ---- bf16 MFMA GEMM: hb[40000][256] = bf16(xb @ W) ------------------------
__global__ __launch_bounds__(256) void k_gemmb(const unsigned short* __restrict__ xb,
                                               const unsigned short* __restrict__ wt2,
                                               unsigned short* __restrict__ hb) {
  __shared__ __attribute__((aligned(16))) unsigned short Alds[64][40];
  __shared__ __attribute__((aligned(16))) unsigned short Blds[256][40];
  int tid = threadIdx.x;
  int wave = tid >> 6, lane = tid & 63;
  int l15 = lane & 15, l16 = lane >> 4;
  int row0 = blockIdx.x * 64;
  f32x4 acc[4][4] = {};
  int ar = tid >> 2, ac = (tid & 3) * 8;
  const unsigned short* aglob = xb + (size_t)(row0 + ar) * 256 + ac;
  for (int kt = 0; kt < 8; ++kt) {
    short8 av = *(const short8*)(aglob + kt * 32);
    *(short8*)(&Alds[ar][ac]) = av;
    const unsigned short* bsrc = wt2 + kt * (256 * 32);
#pragma unroll
    for (int i = 0; i < 4; ++i) {
      int cidx = tid + 256 * i;
      short8 bv = *(const short8*)(bsrc + cidx * 8);
      *(short8*)(&Blds[cidx >> 2][(cidx & 3) * 8]) = bv;
    }
    __syncthreads();
    short8 af[4], bf[4];
#pragma unroll
    for (int mt = 0; mt < 4; ++mt) af[mt] = *(const short8*)(&Alds[mt * 16 + l15][l16 * 8]);
#pragma unroll
    for (int nt = 0; nt < 4; ++nt) bf[nt] = *(const short8*)(&Blds[wave * 64 + nt * 16 + l15][l16 * 8]);
#pragma unroll
    for (int mt = 0; mt < 4; ++mt)
#pragma unroll
      for (int nt = 0; nt < 4; ++nt)
        acc[mt][nt] = __builtin_amdgcn_mfma_f32_16x16x32_bf16(af[mt], bf[nt], acc[mt][nt], 0, 0, 0);
    __syncthreads();
  }
#pragma unroll
  for (int mt = 0; mt < 4; ++mt)
#pragma unroll
    for (int nt = 0; nt < 4; ++nt)
#pragma unroll
      for (int rr = 0; rr < 4; ++rr)
        hb[(size_t)(row0 + mt * 16 + l16 * 4 + rr) * 256 + wave * 64 + nt * 16 + l15] =
            f2bf(acc[mt][nt][rr]);
}

// ---- per-dst-node softmax + aggregation (one wave per node) ---------------
// alsrc/aldst have per-node stride 64 (pre-offset to the right q*8 column)
__global__ __launch_bounds__(256) void k_agg(
    const int* __restrict__ rowptr, const int* __restrict__ adj,
    const float* __restrict__ alsrc, const float* __restrict__ aldst,
    const unsigned short* __restrict__ hb, const float* __restrict__ bias,
    float* __restrict__ out, int mode) {
  int wave = threadIdx.x >> 6, lane = threadIdx.x & 63;
  int d = blockIdx.x * 4 + wave;
  int hl = lane >> 3;
  int beg = rowptr[d], end = rowptr[d + 1];
  float adst = aldst[(size_t)d * 64 + hl];
  float eself = alsrc[(size_t)d * 64 + hl] + adst;
  eself = eself >= 0.f ? eself : 0.2f * eself;
  float m = eself;
  for (int j = beg; j < end; ++j) {
    int s = adj[j];
    float e = alsrc[(size_t)s * 64 + hl] + adst;
    e = e >= 0.f ? e : 0.2f * e;
    m = fmaxf(m, e);
  }
  float ssum = 0.f;
  f32x4 acc = {0.f, 0.f, 0.f, 0.f};
  {
    float w = __expf(eself - m);
    ssum += w;
    f32x4 hv = ld_bf4(hb + (size_t)d * 256 + lane * 4);
#pragma unroll
    for (int i = 0; i < 4; ++i) acc[i] += w * hv[i];
  }
  for (int j = beg; j < end; ++j) {
    int s = adj[j];
    float e = alsrc[(size_t)s * 64 + hl] + adst;
    e = e >= 0.f ? e : 0.2f * e;
    float w = __expf(e - m);
    ssum += w;
    f32x4 hv = ld_bf4(hb + (size_t)s * 256 + lane * 4);
#pragma unroll
    for (int i = 0; i < 4; ++i) acc[i] += w * hv[i];
  }
  float inv = 1.f / ssum;
  f32x4 bv = *(const f32x4*)(bias + lane * 4);
  f32x4 res;
#pragma unroll
  for (int i = 0; i < 4; ++i) res[i] = acc[i] * inv + bv[i];
  float* op = out + (size_t)d * 256 + lane * 4;
  if (mode == 1) {
    f32x4 prev = *(const f32x4*)op;
#pragma unroll
    for (int i = 0; i < 4; ++i) res[i] = 0.5f * (prev[i] + res[i]);
  }
  *(f32x4*)op = res;
}

extern "C" void kernel_launch(void* const* d_in, const int* in_sizes, int n_in,
                              void* d_out, int out_size, void* d_ws, size_t ws_size,
                              hipStream_t stream) {
  (void)in_sizes; (void)n_in; (void)out_size; (void)ws_size;
  const float* x[6];
  for (int i = 0; i < 6; ++i) x[i] = (const float*)d_in[i];
  const float* W = (const float*)d_in[6];
  const float* att_src = (const float*)d_in[7];
  const float* att_dst = (const float*)d_in[8];
  const float* bias = (const float*)d_in[9];
  const int* ei[4] = {(const int*)d_in[10], (const int*)d_in[11],
                      (const int*)d_in[12], (const int*)d_in[13]};
  float* out = (float*)d_out;

  char* ws = (char*)d_ws;
  size_t off = 0;
  auto take = [&](size_t bytes) -> char* {
    char* p = ws + off;
    off += (bytes + 255) & ~(size_t)255;
    return p;
  };
  unsigned short* xb = (unsigned short*)take(6ull * NN * 256 * 2);   // 122.9 MB
  unsigned short* hb = (unsigned short*)take((size_t)NN * 256 * 2);  // 20.5 MB
  float* alx = (float*)take(6ull * NN * 64 * 4);                     // 61.4 MB
  unsigned short* wt2 = (unsigned short*)take(4ull * 8 * 256 * 32 * 2);
  float* weff = (float*)take(8ull * 256 * 8 * 4);
  unsigned short* weffb = (unsigned short*)take(8ull * 64 * 32 * 2);
  int* cnt = (int*)take(4ull * NN * 4);
  int* rowptr = (int*)take(4ull * (NN + 1) * 4);
  int* cursor = (int*)take(4ull * NN * 4);
  int* adj = (int*)take(4ull * EE * 4);

  k_convx<<<dim3(10000, 6), 256, 0, stream>>>(x[0], x[1], x[2], x[3], x[4], x[5], xb);
  k_wt2<<<dim3(1024), 256, 0, stream>>>(W, wt2);
  k_weff<<<dim3(64), 256, 0, stream>>>(W, att_src, att_dst, weff);
  k_weffb<<<dim3(64), 256, 0, stream>>>(weff, weffb);
  k_zero<<<dim3(625), 256, 0, stream>>>(cnt, 4 * NN);
  k_hist<<<dim3((EE + 255) / 256, 4), 256, 0, stream>>>(ei[0], ei[1], ei[2], ei[3], cnt);
  k_scan<<<dim3(4), 1024, 0, stream>>>(cnt, rowptr, cursor);
  k_scatter<<<dim3((EE + 255) / 256, 4), 256, 0, stream>>>(ei[0], ei[1], ei[2], ei[3], cursor, adj);
  k_algemm<<<dim3(625, 6), 256, 0, stream>>>(xb, weffb, alx);

  // relation -> src/dst node type (0=paper,1=author,2=subject)
  const int srct[4] = {0, 1, 0, 2};
  const int dstt[4] = {1, 0, 2, 0};
  // processing order per graph: rel0->author, rel1->paper(write), rel3->paper(combine), rel2->subject
  const int opr[4] = {0, 1, 3, 2};
  const int opsec[4] = {1, 0, 0, 2};
  const int opmode[4] = {0, 0, 1, 0};
  for (int g = 0; g < 2; ++g) {
    for (int k = 0; k < 4; ++k) {
      int r = opr[k];
      const unsigned short* xbp = xb + (size_t)(g * 3 + srct[r]) * (NN * 256);
      const unsigned short* wtp = wt2 + (size_t)r * (8 * 256 * 32);
      k_gemmb<<<dim3(625), 256, 0, stream>>>(xbp, wtp, hb);
      const float* alsrc = alx + (size_t)(g * 3 + srct[r]) * NN * 64 + (size_t)(r * 2) * 8;
      const float* aldst = alx + (size_t)(g * 3 + dstt[r]) * NN * 64 + (size_t)(r * 2 + 1) * 8;
      float* outp = out + ((size_t)g * 3 * NN + (size_t)opsec[k] * NN) * 256;
      k_agg<<<dim3(10000), 256, 0, stream>>>(rowptr + r * (NN + 1), adj + (size_t)r * EE,
                                             alsrc, aldst, hb, bias + r * 256, outp, opmode[k]);
    }
  }
}

// Round 3
// 899.095 us; speedup vs baseline: 1.9973x; 1.3519x over previous
//
#include <hip/hip_runtime.h>

#define NN 40000
#define EE 400000

typedef short short8 __attribute__((ext_vector_type(8)));
typedef float f32x4 __attribute__((ext_vector_type(4)));
typedef unsigned short ushort4_ __attribute__((ext_vector_type(4)));

__device__ __forceinline__ unsigned short f2bf(float f) {
  unsigned int u = __float_as_uint(f);
  u = (u + 0x7FFFu + ((u >> 16) & 1u)) >> 16;
  return (unsigned short)u;
}

__device__ __forceinline__ f32x4 ld_bf4(const unsigned short* p) {
  ushort4_ u = *(const ushort4_*)p;
  f32x4 r;
  r[0] = __uint_as_float((unsigned int)u[0] << 16);
  r[1] = __uint_as_float((unsigned int)u[1] << 16);
  r[2] = __uint_as_float((unsigned int)u[2] << 16);
  r[3] = __uint_as_float((unsigned int)u[3] << 16);
  return r;
}

// ---- f32 -> bf16 for the 6 node-feature matrices --------------------------
__global__ __launch_bounds__(256) void k_convx(
    const float* __restrict__ x0, const float* __restrict__ x1, const float* __restrict__ x2,
    const float* __restrict__ x3, const float* __restrict__ x4, const float* __restrict__ x5,
    unsigned short* __restrict__ xb) {
  int z = blockIdx.y;
  const float* x;
  switch (z) { case 0: x = x0; break; case 1: x = x1; break; case 2: x = x2; break;
               case 3: x = x3; break; case 4: x = x4; break; default: x = x5; break; }
  size_t i = ((size_t)blockIdx.x * 256 + threadIdx.x) * 4;
  f32x4 v = *(const f32x4*)(x + i);
  ushort4_ o;
  o[0] = f2bf(v[0]); o[1] = f2bf(v[1]); o[2] = f2bf(v[2]); o[3] = f2bf(v[3]);
  *(ushort4_*)(xb + (size_t)z * (NN * 256) + i) = o;
}

// ---- W -> bf16, k-tiled transposed: wt2[r][kt][n][k0] = W[r][kt*32+k0][n] --
__global__ __launch_bounds__(256) void k_wt2(const float* __restrict__ W,
                                             unsigned short* __restrict__ wt2) {
  int idx = blockIdx.x * 256 + threadIdx.x;  // < 262144
  int k0 = idx & 31, n = (idx >> 5) & 255, kt = (idx >> 13) & 7, r = idx >> 16;
  float v = W[((size_t)(r * 256) + (kt * 32 + k0)) * 256 + n];
  wt2[idx] = f2bf(v);
}

// ---- weff[q][f][j] = sum_c W[r][f][j*32+c] * att[r][j][c], q = r*2+side ----
__global__ __launch_bounds__(256) void k_weff(const float* __restrict__ W,
                                              const float* __restrict__ asrc,
                                              const float* __restrict__ adst,
                                              float* __restrict__ weff) {
  int idx = blockIdx.x * 256 + threadIdx.x;  // < 16384
  int j = idx & 7, f = (idx >> 3) & 255, q = idx >> 11;
  int r = q >> 1, side = q & 1;
  const float* att = side ? adst : asrc;
  const float* wrow = W + ((size_t)(r * 256) + f) * 256 + j * 32;
  const float* arow = att + (r * 8 + j) * 32;
  float s = 0.f;
#pragma unroll
  for (int c = 0; c < 32; ++c) s += wrow[c] * arow[c];
  weff[idx] = s;
}

// ---- weff -> bf16 k-tiled B layout: weffb[kt][col][k0], col = q*8 + j ------
__global__ __launch_bounds__(256) void k_weffb(const float* __restrict__ weff,
                                               unsigned short* __restrict__ weffb) {
  int idx = blockIdx.x * 256 + threadIdx.x;  // < 16384
  int k0 = idx & 31, col = (idx >> 5) & 63, kt = idx >> 11;
  int q = col >> 3, j = col & 7;
  int f = kt * 32 + k0;
  weffb[idx] = f2bf(weff[(q * 256 + f) * 8 + j]);
}

// ---- CSR build ------------------------------------------------------------
__global__ __launch_bounds__(256) void k_zero(int* __restrict__ p, int n) {
  int i = blockIdx.x * 256 + threadIdx.x;
  if (i < n) p[i] = 0;
}

__global__ __launch_bounds__(256) void k_hist(
    const int* __restrict__ e0, const int* __restrict__ e1,
    const int* __restrict__ e2, const int* __restrict__ e3, int* __restrict__ cnt) {
  int r = blockIdx.y;
  const int* ei = (r == 0) ? e0 : (r == 1) ? e1 : (r == 2) ? e2 : e3;
  int e = blockIdx.x * 256 + threadIdx.x;
  if (e < EE) atomicAdd(&cnt[r * NN + ei[EE + e]], 1);
}

__global__ __launch_bounds__(1024) void k_scan(const int* __restrict__ cnt,
                                               int* __restrict__ rowptr,
                                               int* __restrict__ cursor) {
  int r = blockIdx.x;
  const int* c = cnt + r * NN;
  int* rp = rowptr + r * (NN + 1);
  int* cur = cursor + r * NN;
  __shared__ int part[1024];
  int t = threadIdx.x;
  const int per = 40;  // 1024*40 >= 40000
  int base = t * per;
  int sum = 0;
  for (int i = 0; i < per; ++i) { int idx = base + i; if (idx < NN) sum += c[idx]; }
  part[t] = sum;
  __syncthreads();
  for (int o = 1; o < 1024; o <<= 1) {
    int v = (t >= o) ? part[t - o] : 0;
    __syncthreads();
    part[t] += v;
    __syncthreads();
  }
  int run = part[t] - sum;  // exclusive prefix
  for (int i = 0; i < per; ++i) {
    int idx = base + i;
    if (idx < NN) { rp[idx] = run; cur[idx] = run; run += c[idx]; }
  }
  if (t == 1023) rp[NN] = part[1023];
}

__global__ __launch_bounds__(256) void k_scatter(
    const int* __restrict__ e0, const int* __restrict__ e1,
    const int* __restrict__ e2, const int* __restrict__ e3,
    int* __restrict__ cursor, int* __restrict__ adj) {
  int r = blockIdx.y;
  const int* ei = (r == 0) ? e0 : (r == 1) ? e1 : (r == 2) ? e2 : e3;
  int e = blockIdx.x * 256 + threadIdx.x;
  if (e < EE) {
    int s = ei[e], d = ei[EE + e];
    int pos = atomicAdd(&cursor[r * NN + d], 1);
    adj[(size_t)r * EE + pos] = s;
  }
}

// ---- attention logits via MFMA: alx[z][q][n][8] = (xb[z] @ weffb) ----------
__global__ __launch_bounds__(256) void k_algemm(const unsigned short* __restrict__ xb,
                                                const unsigned short* __restrict__ weffb,
                                                float* __restrict__ alx) {
  __shared__ __attribute__((aligned(16))) unsigned short Alds[64][40];
  __shared__ __attribute__((aligned(16))) unsigned short Blds[64][40];
  int z = blockIdx.y;
  const unsigned short* xbp = xb + (size_t)z * (NN * 256);
  int tid = threadIdx.x;
  int wave = tid >> 6, lane = tid & 63;
  int l15 = lane & 15, l16 = lane >> 4;
  int row0 = blockIdx.x * 64;
  f32x4 acc[4] = {};
  int ar = tid >> 2, ac = (tid & 3) * 8;
  const unsigned short* aglob = xbp + (size_t)(row0 + ar) * 256 + ac;
  for (int kt = 0; kt < 8; ++kt) {
    short8 av = *(const short8*)(aglob + kt * 32);
    *(short8*)(&Alds[ar][ac]) = av;
    short8 bv = *(const short8*)(weffb + kt * 2048 + tid * 8);
    *(short8*)(&Blds[tid >> 2][(tid & 3) * 8]) = bv;
    __syncthreads();
    short8 bf = *(const short8*)(&Blds[wave * 16 + l15][l16 * 8]);
#pragma unroll
    for (int mt = 0; mt < 4; ++mt) {
      short8 af = *(const short8*)(&Alds[mt * 16 + l15][l16 * 8]);
      acc[mt] = __builtin_amdgcn_mfma_f32_16x16x32_bf16(af, bf, acc[mt], 0, 0, 0);
    }
    __syncthreads();
  }
  int col = wave * 16 + l15;
  int q = col >> 3, jj = col & 7;
#pragma unroll
  for (int mt = 0; mt < 4; ++mt)
#pragma unroll
    for (int rr = 0; rr < 4; ++rr) {
      int row = row0 + mt * 16 + l16 * 4 + rr;
      alx[(((size_t)z * 8 + q) * NN + row) * 8 + jj] = acc[mt][rr];
    }
}

// ---- bf16 MFMA GEMM (batched over r): hb[r][40000][256] = bf16(xb @ W) ----
__global__ __launch_bounds__(256) void k_gemmb4(const unsigned short* __restrict__ xb,
                                                const unsigned short* __restrict__ wt2,
                                                unsigned short* __restrict__ hb4, int g) {
  __shared__ __attribute__((aligned(16))) unsigned short Alds[64][40];
  __shared__ __attribute__((aligned(16))) unsigned short Blds[256][40];
  const int srct[4] = {0, 1, 0, 2};
  int r = blockIdx.y;
  const unsigned short* xbp = xb + (size_t)(g * 3 + srct[r]) * (NN * 256);
  const unsigned short* wtp = wt2 + (size_t)r * (8 * 256 * 32);
  unsigned short* hbp = hb4 + (size_t)r * (NN * 256);
  int tid = threadIdx.x;
  int wave = tid >> 6, lane = tid & 63;
  int l15 = lane & 15, l16 = lane >> 4;
  int row0 = blockIdx.x * 64;
  f32x4 acc[4][4] = {};
  int ar = tid >> 2, ac = (tid & 3) * 8;
  const unsigned short* aglob = xbp + (size_t)(row0 + ar) * 256 + ac;
  for (int kt = 0; kt < 8; ++kt) {
    short8 av = *(const short8*)(aglob + kt * 32);
    *(short8*)(&Alds[ar][ac]) = av;
    const unsigned short* bsrc = wtp + kt * (256 * 32);
#pragma unroll
    for (int i = 0; i < 4; ++i) {
      int cidx = tid + 256 * i;
      short8 bv = *(const short8*)(bsrc + cidx * 8);
      *(short8*)(&Blds[cidx >> 2][(cidx & 3) * 8]) = bv;
    }
    __syncthreads();
    short8 af[4], bf[4];
#pragma unroll
    for (int mt = 0; mt < 4; ++mt) af[mt] = *(const short8*)(&Alds[mt * 16 + l15][l16 * 8]);
#pragma unroll
    for (int nt = 0; nt < 4; ++nt) bf[nt] = *(const short8*)(&Blds[wave * 64 + nt * 16 + l15][l16 * 8]);
#pragma unroll
    for (int mt = 0; mt < 4; ++mt)
#pragma unroll
      for (int nt = 0; nt < 4; ++nt)
        acc[mt][nt] = __builtin_amdgcn_mfma_f32_16x16x32_bf16(af[mt], bf[nt], acc[mt][nt], 0, 0, 0);
    __syncthreads();
  }
#pragma unroll
  for (int mt = 0; mt < 4; ++mt)
#pragma unroll
    for (int nt = 0; nt < 4; ++nt)
#pragma unroll
      for (int rr = 0; rr < 4; ++rr)
        hbp[(size_t)(row0 + mt * 16 + l16 * 4 + rr) * 256 + wave * 64 + nt * 16 + l15] =
            f2bf(acc[mt][nt][rr]);
}

// ---- online-softmax aggregation, 8-edge-parallel groups -------------------
// lane layout: head h = lane>>3 (matches feature chunk lane*4), edge slot e8 = lane&7
__global__ __launch_bounds__(256) void k_agg3(
    const int* __restrict__ rowptr4, const int* __restrict__ adj4,
    const float* __restrict__ alx, const unsigned short* __restrict__ hb4,
    const float* __restrict__ bias, float* __restrict__ out, int g, int pass) {
  const int srct[4] = {0, 1, 0, 2};
  const int dstt[4] = {1, 0, 2, 0};
  const int sect[4] = {1, 0, 2, 0};
  int r = pass ? 3 : (int)blockIdx.y;
  int wave = threadIdx.x >> 6, lane = threadIdx.x & 63;
  int d = blockIdx.x * 4 + wave;
  int h = lane >> 3, e8 = lane & 7;
  const int* rowptr = rowptr4 + r * (NN + 1);
  const int* adj = adj4 + (size_t)r * EE;
  const float* alsrc = alx + ((size_t)((g * 3 + srct[r]) * 8 + 2 * r) * NN) * 8;
  const float* aldst = alx + ((size_t)((g * 3 + dstt[r]) * 8 + 2 * r + 1) * NN) * 8;
  const unsigned short* hb = hb4 + (size_t)r * (NN * 256);
  const float* bs = bias + r * 256;
  float* outp = out + (size_t)(g * 3 + sect[r]) * NN * 256;

  int beg = rowptr[d], end = rowptr[d + 1];
  float adst = aldst[(size_t)d * 8 + h];
  float es = alsrc[(size_t)d * 8 + h] + adst;
  es = es >= 0.f ? es : 0.2f * es;
  float m = es;
  float ssum = (e8 == 0) ? 1.0f : 0.0f;  // self-loop weight exp(0)=1, once per octet
  f32x4 acc = ld_bf4(hb + (size_t)d * 256 + lane * 4);  // self contribution (w=1)

  for (int j0 = beg; j0 < end; j0 += 8) {
    int j = j0 + e8;
    bool valid = j < end;
    int s = valid ? adj[j] : 0;
    float e = -1e30f;
    if (valid) {
      float t = alsrc[(size_t)s * 8 + h] + adst;
      e = t >= 0.f ? t : 0.2f * t;
    }
    // group max across edge slots (octet-local)
    float gm = e;
    gm = fmaxf(gm, __shfl_xor(gm, 1, 64));
    gm = fmaxf(gm, __shfl_xor(gm, 2, 64));
    gm = fmaxf(gm, __shfl_xor(gm, 4, 64));
    float mn = fmaxf(m, gm);
    float sc = __expf(m - mn);
    m = mn;
    ssum *= sc;
#pragma unroll
    for (int i = 0; i < 4; ++i) acc[i] *= sc;
    float w = valid ? __expf(e - m) : 0.f;
    ssum += w;
    int nv = end - j0;
    if (nv > 8) nv = 8;
    for (int e2 = 0; e2 < nv; ++e2) {
      int se = __shfl(s, e2, 64);
      float we = __shfl(w, e2 | (lane & 56), 64);
      f32x4 hv = ld_bf4(hb + (size_t)se * 256 + lane * 4);
#pragma unroll
      for (int i = 0; i < 4; ++i) acc[i] += we * hv[i];
    }
  }
  ssum += __shfl_xor(ssum, 1, 64);
  ssum += __shfl_xor(ssum, 2, 64);
  ssum += __shfl_xor(ssum, 4, 64);
  float inv = 1.f / ssum;
  f32x4 bv = *(const f32x4*)(bs + lane * 4);
  f32x4 res;
#pragma unroll
  for (int i = 0; i < 4; ++i) res[i] = acc[i] * inv + bv[i];
  float* op = outp + (size_t)d * 256 + lane * 4;
  if (pass) {
    f32x4 prev = *(const f32x4*)op;
#pragma unroll
    for (int i = 0; i < 4; ++i) res[i] = 0.5f * (prev[i] + res[i]);
  }
  *(f32x4*)op = res;
}

extern "C" void kernel_launch(void* const* d_in, const int* in_sizes, int n_in,
                              void* d_out, int out_size, void* d_ws, size_t ws_size,
                              hipStream_t stream) {
  (void)in_sizes; (void)n_in; (void)out_size; (void)ws_size;
  const float* x[6];
  for (int i = 0; i < 6; ++i) x[i] = (const float*)d_in[i];
  const float* W = (const float*)d_in[6];
  const float* att_src = (const float*)d_in[7];
  const float* att_dst = (const float*)d_in[8];
  const float* bias = (const float*)d_in[9];
  const int* ei[4] = {(const int*)d_in[10], (const int*)d_in[11],
                      (const int*)d_in[12], (const int*)d_in[13]};
  float* out = (float*)d_out;

  char* ws = (char*)d_ws;
  size_t off = 0;
  auto take = [&](size_t bytes) -> char* {
    char* p = ws + off;
    off += (bytes + 255) & ~(size_t)255;
    return p;
  };
  unsigned short* xb = (unsigned short*)take(6ull * NN * 256 * 2);    // 122.9 MB
  unsigned short* hb = (unsigned short*)take(4ull * NN * 256 * 2);    // 81.9 MB
  float* alx = (float*)take(6ull * NN * 64 * 4);                      // 61.4 MB
  unsigned short* wt2 = (unsigned short*)take(4ull * 8 * 256 * 32 * 2);
  float* weff = (float*)take(8ull * 256 * 8 * 4);
  unsigned short* weffb = (unsigned short*)take(8ull * 64 * 32 * 2);
  int* cnt = (int*)take(4ull * NN * 4);
  int* rowptr = (int*)take(4ull * (NN + 1) * 4);
  int* cursor = (int*)take(4ull * NN * 4);
  int* adj = (int*)take(4ull * EE * 4);

  k_convx<<<dim3(10000, 6), 256, 0, stream>>>(x[0], x[1], x[2], x[3], x[4], x[5], xb);
  k_wt2<<<dim3(1024), 256, 0, stream>>>(W, wt2);
  k_weff<<<dim3(64), 256, 0, stream>>>(W, att_src, att_dst, weff);
  k_weffb<<<dim3(64), 256, 0, stream>>>(weff, weffb);
  k_zero<<<dim3(625), 256, 0, stream>>>(cnt, 4 * NN);
  k_hist<<<dim3((EE + 255) / 256, 4), 256, 0, stream>>>(ei[0], ei[1], ei[2], ei[3], cnt);
  k_scan<<<dim3(4), 1024, 0, stream>>>(cnt, rowptr, cursor);
  k_scatter<<<dim3((EE + 255) / 256, 4), 256, 0, stream>>>(ei[0], ei[1], ei[2], ei[3], cursor, adj);
  k_algemm<<<dim3(625, 6), 256, 0, stream>>>(xb, weffb, alx);

  for (int g = 0; g < 2; ++g) {
    k_gemmb4<<<dim3(625, 4), 256, 0, stream>>>(xb, wt2, hb, g);
    k_agg3<<<dim3(10000, 3), 256, 0, stream>>>(rowptr, adj, alx, hb, bias, out, g, 0);
    k_agg3<<<dim3(10000, 1), 256, 0, stream>>>(rowptr, adj, alx, hb, bias, out, g, 1);
  }
}

// Round 4
// 879.339 us; speedup vs baseline: 2.0422x; 1.0225x over previous
//
#include <hip/hip_runtime.h>

#define NN 40000
#define EE 400000

typedef short short8 __attribute__((ext_vector_type(8)));
typedef float f32x4 __attribute__((ext_vector_type(4)));
typedef unsigned short ushort4_ __attribute__((ext_vector_type(4)));

__device__ __forceinline__ unsigned short f2bf(float f) {
  unsigned int u = __float_as_uint(f);
  u = (u + 0x7FFFu + ((u >> 16) & 1u)) >> 16;
  return (unsigned short)u;
}

__device__ __forceinline__ f32x4 ld_bf4(const unsigned short* p) {
  ushort4_ u = *(const ushort4_*)p;
  f32x4 r;
  r[0] = __uint_as_float((unsigned int)u[0] << 16);
  r[1] = __uint_as_float((unsigned int)u[1] << 16);
  r[2] = __uint_as_float((unsigned int)u[2] << 16);
  r[3] = __uint_as_float((unsigned int)u[3] << 16);
  return r;
}

// ---- f32 -> bf16 for the 6 node-feature matrices --------------------------
__global__ __launch_bounds__(256) void k_convx(
    const float* __restrict__ x0, const float* __restrict__ x1, const float* __restrict__ x2,
    const float* __restrict__ x3, const float* __restrict__ x4, const float* __restrict__ x5,
    unsigned short* __restrict__ xb) {
  int z = blockIdx.y;
  const float* x;
  switch (z) { case 0: x = x0; break; case 1: x = x1; break; case 2: x = x2; break;
               case 3: x = x3; break; case 4: x = x4; break; default: x = x5; break; }
  size_t i = ((size_t)blockIdx.x * 256 + threadIdx.x) * 4;
  f32x4 v = *(const f32x4*)(x + i);
  ushort4_ o;
  o[0] = f2bf(v[0]); o[1] = f2bf(v[1]); o[2] = f2bf(v[2]); o[3] = f2bf(v[3]);
  *(ushort4_*)(xb + (size_t)z * (NN * 256) + i) = o;
}

// ---- W -> bf16, k-tiled transposed: wt2[r][kt][n][k0] = W[r][kt*32+k0][n] --
__global__ __launch_bounds__(256) void k_wt2(const float* __restrict__ W,
                                             unsigned short* __restrict__ wt2) {
  int idx = blockIdx.x * 256 + threadIdx.x;  // < 262144
  int k0 = idx & 31, n = (idx >> 5) & 255, kt = (idx >> 13) & 7, r = idx >> 16;
  float v = W[((size_t)(r * 256) + (kt * 32 + k0)) * 256 + n];
  wt2[idx] = f2bf(v);
}

// ---- weff[q][f][j] = sum_c W[r][f][j*32+c] * att[r][j][c], q = r*2+side ----
__global__ __launch_bounds__(256) void k_weff(const float* __restrict__ W,
                                              const float* __restrict__ asrc,
                                              const float* __restrict__ adst,
                                              float* __restrict__ weff) {
  int idx = blockIdx.x * 256 + threadIdx.x;  // < 16384
  int j = idx & 7, f = (idx >> 3) & 255, q = idx >> 11;
  int r = q >> 1, side = q & 1;
  const float* att = side ? adst : asrc;
  const float* wrow = W + ((size_t)(r * 256) + f) * 256 + j * 32;
  const float* arow = att + (r * 8 + j) * 32;
  float s = 0.f;
#pragma unroll
  for (int c = 0; c < 32; ++c) s += wrow[c] * arow[c];
  weff[idx] = s;
}

// ---- weff -> bf16 k-tiled B layout: weffb[kt][col][k0], col = q*8 + j ------
__global__ __launch_bounds__(256) void k_weffb(const float* __restrict__ weff,
                                               unsigned short* __restrict__ weffb) {
  int idx = blockIdx.x * 256 + threadIdx.x;  // < 16384
  int k0 = idx & 31, col = (idx >> 5) & 63, kt = idx >> 11;
  int q = col >> 3, j = col & 7;
  int f = kt * 32 + k0;
  weffb[idx] = f2bf(weff[(q * 256 + f) * 8 + j]);
}

// ---- CSR build ------------------------------------------------------------
__global__ __launch_bounds__(256) void k_zero(int* __restrict__ p, int n) {
  int i = blockIdx.x * 256 + threadIdx.x;
  if (i < n) p[i] = 0;
}

__global__ __launch_bounds__(256) void k_hist(
    const int* __restrict__ e0, const int* __restrict__ e1,
    const int* __restrict__ e2, const int* __restrict__ e3, int* __restrict__ cnt) {
  int r = blockIdx.y;
  const int* ei = (r == 0) ? e0 : (r == 1) ? e1 : (r == 2) ? e2 : e3;
  int e = blockIdx.x * 256 + threadIdx.x;
  if (e < EE) atomicAdd(&cnt[r * NN + ei[EE + e]], 1);
}

__global__ __launch_bounds__(1024) void k_scan(const int* __restrict__ cnt,
                                               int* __restrict__ rowptr,
                                               int* __restrict__ cursor) {
  int r = blockIdx.x;
  const int* c = cnt + r * NN;
  int* rp = rowptr + r * (NN + 1);
  int* cur = cursor + r * NN;
  __shared__ int part[1024];
  int t = threadIdx.x;
  const int per = 40;  // 1024*40 >= 40000
  int base = t * per;
  int sum = 0;
  for (int i = 0; i < per; ++i) { int idx = base + i; if (idx < NN) sum += c[idx]; }
  part[t] = sum;
  __syncthreads();
  for (int o = 1; o < 1024; o <<= 1) {
    int v = (t >= o) ? part[t - o] : 0;
    __syncthreads();
    part[t] += v;
    __syncthreads();
  }
  int run = part[t] - sum;  // exclusive prefix
  for (int i = 0; i < per; ++i) {
    int idx = base + i;
    if (idx < NN) { rp[idx] = run; cur[idx] = run; run += c[idx]; }
  }
  if (t == 1023) rp[NN] = part[1023];
}

__global__ __launch_bounds__(256) void k_scatter(
    const int* __restrict__ e0, const int* __restrict__ e1,
    const int* __restrict__ e2, const int* __restrict__ e3,
    int* __restrict__ cursor, int* __restrict__ adj) {
  int r = blockIdx.y;
  const int* ei = (r == 0) ? e0 : (r == 1) ? e1 : (r == 2) ? e2 : e3;
  int e = blockIdx.x * 256 + threadIdx.x;
  if (e < EE) {
    int s = ei[e], d = ei[EE + e];
    int pos = atomicAdd(&cursor[r * NN + d], 1);
    adj[(size_t)r * EE + pos] = s;
  }
}

// ---- attention logits via MFMA: alx[z][q][n][8] = (xb[z] @ weffb) ----------
__global__ __launch_bounds__(256) void k_algemm(const unsigned short* __restrict__ xb,
                                                const unsigned short* __restrict__ weffb,
                                                float* __restrict__ alx) {
  __shared__ __attribute__((aligned(16))) unsigned short Alds[64][40];
  __shared__ __attribute__((aligned(16))) unsigned short Blds[64][40];
  int z = blockIdx.y;
  const unsigned short* xbp = xb + (size_t)z * (NN * 256);
  int tid = threadIdx.x;
  int wave = tid >> 6, lane = tid & 63;
  int l15 = lane & 15, l16 = lane >> 4;
  int row0 = blockIdx.x * 64;
  f32x4 acc[4] = {};
  int ar = tid >> 2, ac = (tid & 3) * 8;
  const unsigned short* aglob = xbp + (size_t)(row0 + ar) * 256 + ac;
  for (int kt = 0; kt < 8; ++kt) {
    short8 av = *(const short8*)(aglob + kt * 32);
    *(short8*)(&Alds[ar][ac]) = av;
    short8 bv = *(const short8*)(weffb + kt * 2048 + tid * 8);
    *(short8*)(&Blds[tid >> 2][(tid & 3) * 8]) = bv;
    __syncthreads();
    short8 bf = *(const short8*)(&Blds[wave * 16 + l15][l16 * 8]);
#pragma unroll
    for (int mt = 0; mt < 4; ++mt) {
      short8 af = *(const short8*)(&Alds[mt * 16 + l15][l16 * 8]);
      acc[mt] = __builtin_amdgcn_mfma_f32_16x16x32_bf16(af, bf, acc[mt], 0, 0, 0);
    }
    __syncthreads();
  }
  int col = wave * 16 + l15;
  int q = col >> 3, jj = col & 7;
#pragma unroll
  for (int mt = 0; mt < 4; ++mt)
#pragma unroll
    for (int rr = 0; rr < 4; ++rr) {
      int row = row0 + mt * 16 + l16 * 4 + rr;
      alx[(((size_t)z * 8 + q) * NN + row) * 8 + jj] = acc[mt][rr];
    }
}

// ---- bf16 MFMA GEMM (batched over r): hb[r][40000][256] = bf16(xb @ W) ----
__global__ __launch_bounds__(256) void k_gemmb4(const unsigned short* __restrict__ xb,
                                                const unsigned short* __restrict__ wt2,
                                                unsigned short* __restrict__ hb4, int g) {
  __shared__ __attribute__((aligned(16))) unsigned short Alds[64][40];
  __shared__ __attribute__((aligned(16))) unsigned short Blds[256][40];
  const int srct[4] = {0, 1, 0, 2};
  int r = blockIdx.y;
  const unsigned short* xbp = xb + (size_t)(g * 3 + srct[r]) * (NN * 256);
  const unsigned short* wtp = wt2 + (size_t)r * (8 * 256 * 32);
  unsigned short* hbp = hb4 + (size_t)r * (NN * 256);
  int tid = threadIdx.x;
  int wave = tid >> 6, lane = tid & 63;
  int l15 = lane & 15, l16 = lane >> 4;
  int row0 = blockIdx.x * 64;
  f32x4 acc[4][4] = {};
  int ar = tid >> 2, ac = (tid & 3) * 8;
  const unsigned short* aglob = xbp + (size_t)(row0 + ar) * 256 + ac;
  for (int kt = 0; kt < 8; ++kt) {
    short8 av = *(const short8*)(aglob + kt * 32);
    *(short8*)(&Alds[ar][ac]) = av;
    const unsigned short* bsrc = wtp + kt * (256 * 32);
#pragma unroll
    for (int i = 0; i < 4; ++i) {
      int cidx = tid + 256 * i;
      short8 bv = *(const short8*)(bsrc + cidx * 8);
      *(short8*)(&Blds[cidx >> 2][(cidx & 3) * 8]) = bv;
    }
    __syncthreads();
    short8 af[4], bf[4];
#pragma unroll
    for (int mt = 0; mt < 4; ++mt) af[mt] = *(const short8*)(&Alds[mt * 16 + l15][l16 * 8]);
#pragma unroll
    for (int nt = 0; nt < 4; ++nt) bf[nt] = *(const short8*)(&Blds[wave * 64 + nt * 16 + l15][l16 * 8]);
#pragma unroll
    for (int mt = 0; mt < 4; ++mt)
#pragma unroll
      for (int nt = 0; nt < 4; ++nt)
        acc[mt][nt] = __builtin_amdgcn_mfma_f32_16x16x32_bf16(af[mt], bf[nt], acc[mt][nt], 0, 0, 0);
    __syncthreads();
  }
#pragma unroll
  for (int mt = 0; mt < 4; ++mt)
#pragma unroll
    for (int nt = 0; nt < 4; ++nt)
#pragma unroll
      for (int rr = 0; rr < 4; ++rr)
        hbp[(size_t)(row0 + mt * 16 + l16 * 4 + rr) * 256 + wave * 64 + nt * 16 + l15] =
            f2bf(acc[mt][nt][rr]);
}

// ---- one-relation online-softmax aggregation for dst node d ---------------
// lane layout: head h = lane>>3, edge slot e8 = lane&7; returns normalized
// per-lane feature chunk (+bias).
__device__ __forceinline__ f32x4 agg_one(
    int r, int g, int d, int lane,
    const int* __restrict__ rowptr4, const int* __restrict__ adj4,
    const float* __restrict__ alx, const unsigned short* __restrict__ hb4,
    const float* __restrict__ bias) {
  const int srct[4] = {0, 1, 0, 2};
  const int dstt[4] = {1, 0, 2, 0};
  int h = lane >> 3, e8 = lane & 7, ob = lane & 56;
  const int* rowptr = rowptr4 + r * (NN + 1);
  const int* adj = adj4 + (size_t)r * EE;
  const float* alsrc = alx + ((size_t)((g * 3 + srct[r]) * 8 + 2 * r) * NN) * 8;
  const float* aldst = alx + ((size_t)((g * 3 + dstt[r]) * 8 + 2 * r + 1) * NN) * 8;
  const unsigned short* hb = hb4 + (size_t)r * (NN * 256);

  int beg = rowptr[d], end = rowptr[d + 1];
  float adst = aldst[(size_t)d * 8 + h];
  float es = alsrc[(size_t)d * 8 + h] + adst;
  es = es >= 0.f ? es : 0.2f * es;
  float m = es;
  float ssum = (e8 == 0) ? 1.0f : 0.0f;          // self-loop, once per octet
  f32x4 acc = ld_bf4(hb + (size_t)d * 256 + lane * 4);

  for (int j0 = beg; j0 < end; j0 += 8) {
    int j = j0 + e8;
    bool valid = j < end;
    int s = valid ? adj[j] : d;                  // clamp invalid to hot self row
    float t = alsrc[(size_t)s * 8 + h] + adst;
    t = t >= 0.f ? t : 0.2f * t;
    float e = valid ? t : -1e30f;
    float gm = e;
    gm = fmaxf(gm, __shfl_xor(gm, 1, 64));
    gm = fmaxf(gm, __shfl_xor(gm, 2, 64));
    gm = fmaxf(gm, __shfl_xor(gm, 4, 64));
    float mn = fmaxf(m, gm);
    float sc = __expf(m - mn);
    m = mn;
    ssum *= sc;
#pragma unroll
    for (int i = 0; i < 4; ++i) acc[i] *= sc;
    float w = valid ? __expf(e - mn) : 0.f;
    ssum += w;
#pragma unroll
    for (int e2 = 0; e2 < 8; ++e2) {
      int se = __shfl(s, ob + e2, 64);
      float we = __shfl(w, ob + e2, 64);
      f32x4 hv = ld_bf4(hb + (size_t)se * 256 + lane * 4);
#pragma unroll
      for (int i = 0; i < 4; ++i) acc[i] += we * hv[i];
    }
  }
  ssum += __shfl_xor(ssum, 1, 64);
  ssum += __shfl_xor(ssum, 2, 64);
  ssum += __shfl_xor(ssum, 4, 64);
  float inv = 1.f / ssum;
  f32x4 bv = *(const f32x4*)(bias + r * 256 + lane * 4);
  f32x4 res;
#pragma unroll
  for (int i = 0; i < 4; ++i) res[i] = acc[i] * inv + bv[i];
  return res;
}

// ---- all four relations per graph in one dispatch -------------------------
// y=0: r0 -> author; y=1: 0.5*(r1+r3) -> paper; y=2: r2 -> subject
__global__ __launch_bounds__(256) void k_agg4(
    const int* __restrict__ rowptr4, const int* __restrict__ adj4,
    const float* __restrict__ alx, const unsigned short* __restrict__ hb4,
    const float* __restrict__ bias, float* __restrict__ out, int g) {
  int wave = threadIdx.x >> 6, lane = threadIdx.x & 63;
  int d = blockIdx.x * 4 + wave;
  int y = blockIdx.y;
  f32x4 res;
  int sec;
  if (y == 1) {
    f32x4 r1 = agg_one(1, g, d, lane, rowptr4, adj4, alx, hb4, bias);
    f32x4 r3 = agg_one(3, g, d, lane, rowptr4, adj4, alx, hb4, bias);
#pragma unroll
    for (int i = 0; i < 4; ++i) res[i] = 0.5f * (r1[i] + r3[i]);
    sec = 0;
  } else {
    int r = (y == 0) ? 0 : 2;
    res = agg_one(r, g, d, lane, rowptr4, adj4, alx, hb4, bias);
    sec = (y == 0) ? 1 : 2;
  }
  *(f32x4*)(out + ((size_t)(g * 3 + sec) * NN + d) * 256 + lane * 4) = res;
}

extern "C" void kernel_launch(void* const* d_in, const int* in_sizes, int n_in,
                              void* d_out, int out_size, void* d_ws, size_t ws_size,
                              hipStream_t stream) {
  (void)in_sizes; (void)n_in; (void)out_size; (void)ws_size;
  const float* x[6];
  for (int i = 0; i < 6; ++i) x[i] = (const float*)d_in[i];
  const float* W = (const float*)d_in[6];
  const float* att_src = (const float*)d_in[7];
  const float* att_dst = (const float*)d_in[8];
  const float* bias = (const float*)d_in[9];
  const int* ei[4] = {(const int*)d_in[10], (const int*)d_in[11],
                      (const int*)d_in[12], (const int*)d_in[13]};
  float* out = (float*)d_out;

  char* ws = (char*)d_ws;
  size_t off = 0;
  auto take = [&](size_t bytes) -> char* {
    char* p = ws + off;
    off += (bytes + 255) & ~(size_t)255;
    return p;
  };
  unsigned short* xb = (unsigned short*)take(6ull * NN * 256 * 2);    // 122.9 MB
  unsigned short* hb = (unsigned short*)take(4ull * NN * 256 * 2);    // 81.9 MB
  float* alx = (float*)take(6ull * NN * 64 * 4);                      // 61.4 MB
  unsigned short* wt2 = (unsigned short*)take(4ull * 8 * 256 * 32 * 2);
  float* weff = (float*)take(8ull * 256 * 8 * 4);
  unsigned short* weffb = (unsigned short*)take(8ull * 64 * 32 * 2);
  int* cnt = (int*)take(4ull * NN * 4);
  int* rowptr = (int*)take(4ull * (NN + 1) * 4);
  int* cursor = (int*)take(4ull * NN * 4);
  int* adj = (int*)take(4ull * EE * 4);

  k_convx<<<dim3(10000, 6), 256, 0, stream>>>(x[0], x[1], x[2], x[3], x[4], x[5], xb);
  k_wt2<<<dim3(1024), 256, 0, stream>>>(W, wt2);
  k_weff<<<dim3(64), 256, 0, stream>>>(W, att_src, att_dst, weff);
  k_weffb<<<dim3(64), 256, 0, stream>>>(weff, weffb);
  k_zero<<<dim3(625), 256, 0, stream>>>(cnt, 4 * NN);
  k_hist<<<dim3((EE + 255) / 256, 4), 256, 0, stream>>>(ei[0], ei[1], ei[2], ei[3], cnt);
  k_scan<<<dim3(4), 1024, 0, stream>>>(cnt, rowptr, cursor);
  k_scatter<<<dim3((EE + 255) / 256, 4), 256, 0, stream>>>(ei[0], ei[1], ei[2], ei[3], cursor, adj);
  k_algemm<<<dim3(625, 6), 256, 0, stream>>>(xb, weffb, alx);

  for (int g = 0; g < 2; ++g) {
    k_gemmb4<<<dim3(625, 4), 256, 0, stream>>>(xb, wt2, hb, g);
    k_agg4<<<dim3(10000, 3), 256, 0, stream>>>(rowptr, adj, alx, hb, bias, out, g);
  }
}